// Round 3
// baseline (289.151 us; speedup 1.0000x reference)
//
#include <hip/hip_runtime.h>
#include <hip/hip_bf16.h>
#include <math.h>

#define Bg   128
#define Nn   64
#define Tt   256
#define INF  320      // Nn + Tt
#define Hd   256
#define OUTD 128
#define Ee   2016     // Nn*(Nn-1)/2
#define TOTE (Bg*Ee)  // 258048
#define SCOLS 520     // S columns: Pm|Qm|Pv|Qv|pw|qw (+pad)
#define TS   34       // LDS row stride for 32-t slice (+2 pad)

typedef __attribute__((ext_vector_type(8))) short bf16x8;
typedef __attribute__((ext_vector_type(4))) float f32x4;

static __device__ __forceinline__ ushort f2bf(float v) {
    __hip_bfloat16 h = __float2bfloat16(v);
    return *(ushort*)&h;
}

// ---------------- edge LUT: e -> (row, col) ----------------
__global__ void k_lut(int2* __restrict__ lut) {
    int e = blockIdx.x * 256 + threadIdx.x;
    if (e >= Ee) return;
    int r = 0;
    while ((r + 1) * (127 - (r + 1)) / 2 <= e) ++r;
    int c = r + 1 + (e - r * (127 - r) / 2);
    lut[e] = make_int2(r, c);
}

// ---------------- fp32 -> bf16 convert ----------------
__global__ void k_cvt(const float* __restrict__ src, ushort* __restrict__ dst, int n) {
    int i = blockIdx.x * 256 + threadIdx.x;
    if (i < n) dst[i] = f2bf(src[i]);
}

// ---------------- pack head weights (bf16): Wcat[K=256][SCOLS] ----------------
__global__ void k_pack(const float* __restrict__ Wm, const float* __restrict__ Wv,
                       const float* __restrict__ Ww, ushort* __restrict__ Wcat) {
    int idx = blockIdx.x * 256 + threadIdx.x;
    if (idx >= Hd * SCOLS) return;
    int k = idx / SCOLS, col = idx - k * SCOLS;
    float v = 0.f;
    if (col < 128)       v = Wm[k * 128 + col];
    else if (col < 256)  v = Wm[(256 + k) * 128 + (col - 128)];
    else if (col < 384)  v = Wv[k * 128 + (col - 256)];
    else if (col < 512)  v = Wv[(256 + k) * 128 + (col - 384)];
    else if (col == 512) v = Ww[k];
    else if (col == 513) v = Ww[256 + k];
    Wcat[idx] = f2bf(v);
}

// ---------------- prefix-mean aggregation -> bf16 ----------------
__global__ void k_agg(const float* __restrict__ topo, const float* __restrict__ temp,
                      ushort* __restrict__ agg) {
    int b = blockIdx.x;
    int f = threadIdx.x;        // 320 threads
    float run = 0.f;
    for (int j = 0; j < Nn; ++j) {
        float v = (j == 0) ? 0.f : run / (float)j;
        agg[(size_t)(b * Nn + j) * INF + f] = f2bf(v);
        float x = (f < Nn) ? topo[(size_t)(b * Nn + j) * Nn + f]
                           : temp[(size_t)(b * Nn + j) * Tt + (f - Nn)];
        run += x;
    }
}

// ---------------- bf16 MFMA GEMM: C = act(A@B + bias) ----------------
// A: MxK bf16 row-major, B: KxN bf16 row-major. Tile 64x64, BK=32, 256 thr.
// Cb!=null -> bf16 out (with bias+relu); else Cf fp32 out. Guard col<N.
__global__ __launch_bounds__(256) void k_gemm_mfma(const ushort* __restrict__ A,
                                                   const ushort* __restrict__ B,
                                                   const float* __restrict__ bias,
                                                   ushort* __restrict__ Cb,
                                                   float* __restrict__ Cf,
                                                   int N, int K, int relu) {
    __shared__ ushort Asl[64 * 32];
    __shared__ ushort Bsl[64 * 32];   // transposed: Bsl[n][k]
    const int tid = threadIdx.x;
    const int w = tid >> 6, lane = tid & 63;
    const int quad = lane >> 4, r16 = lane & 15;
    const int m0 = blockIdx.y * 64, n0 = blockIdx.x * 64;
    const int arow = tid >> 2, aseg = tid & 3;
    const int bk = tid >> 3, bseg = tid & 7;
    f32x4 acc0 = {0,0,0,0}, acc1 = {0,0,0,0}, acc2 = {0,0,0,0}, acc3 = {0,0,0,0};

    for (int k0 = 0; k0 < K; k0 += 32) {
        // stage A tile 64x32
        uint4 av = *(const uint4*)(A + (size_t)(m0 + arow) * K + k0 + aseg * 8);
        *(uint4*)(Asl + arow * 32 + aseg * 8) = av;
        // stage B tile 32x64, transposed into Bsl[n][k]
        int bcol = n0 + bseg * 8;
        uint4 bvv = uint4{0, 0, 0, 0};
        if (bcol < N) bvv = *(const uint4*)(B + (size_t)(k0 + bk) * N + bcol);
        ushort tmp[8];
        *(uint4*)tmp = bvv;
        #pragma unroll
        for (int t = 0; t < 8; ++t) Bsl[(bseg * 8 + t) * 32 + bk] = tmp[t];
        __syncthreads();

        bf16x8 af = *(const bf16x8*)(Asl + (w * 16 + r16) * 32 + quad * 8);
        bf16x8 bf0 = *(const bf16x8*)(Bsl + (0 * 16 + r16) * 32 + quad * 8);
        bf16x8 bf1 = *(const bf16x8*)(Bsl + (1 * 16 + r16) * 32 + quad * 8);
        bf16x8 bf2 = *(const bf16x8*)(Bsl + (2 * 16 + r16) * 32 + quad * 8);
        bf16x8 bf3 = *(const bf16x8*)(Bsl + (3 * 16 + r16) * 32 + quad * 8);
        acc0 = __builtin_amdgcn_mfma_f32_16x16x32_bf16(af, bf0, acc0, 0, 0, 0);
        acc1 = __builtin_amdgcn_mfma_f32_16x16x32_bf16(af, bf1, acc1, 0, 0, 0);
        acc2 = __builtin_amdgcn_mfma_f32_16x16x32_bf16(af, bf2, acc2, 0, 0, 0);
        acc3 = __builtin_amdgcn_mfma_f32_16x16x32_bf16(af, bf3, acc3, 0, 0, 0);
        __syncthreads();
    }

    const int row0 = m0 + w * 16 + quad * 4;
    #pragma unroll
    for (int ns = 0; ns < 4; ++ns) {
        f32x4 a = (ns == 0) ? acc0 : (ns == 1) ? acc1 : (ns == 2) ? acc2 : acc3;
        int col = n0 + ns * 16 + r16;
        if (col >= N) continue;
        #pragma unroll
        for (int i = 0; i < 4; ++i) {
            int row = row0 + i;
            float v = a[i] + (bias ? bias[col] : 0.f);
            if (relu) v = fmaxf(v, 0.f);
            if (Cb) Cb[(size_t)row * N + col] = f2bf(v);
            else    Cf[(size_t)row * N + col] = v;
        }
    }
}

// ---------------- pair-tiled edge partial sums ----------------
// 512 blocks = 128 graphs x 4 t-slices. Block stages 64 nodes x 32 t of the
// 4 needed regions into LDS (bm/bv folded in), then 1024 threads each
// compute a 2x2 node-pair tile over 32 t. Writes partial[tq][edge].
static __device__ __forceinline__ float eterm(float pm, float qm, float pv, float qv) {
    float m = pm + qm;
    float x = pv + qv;
    float sp = fmaxf(x, 0.f) + __logf(1.f + __expf(-fabsf(x)));
    return m * m * __builtin_amdgcn_rcpf(sp + 1.01e-6f);
}

__global__ __launch_bounds__(1024) void k_edge2(const float* __restrict__ S,
                                                const float* __restrict__ bm,
                                                const float* __restrict__ bv,
                                                float* __restrict__ partial) {
    __shared__ float L[4 * 64 * TS];
    const int tq = blockIdx.x & 3, b = blockIdx.x >> 2;
    const int toff = tq * 32;
    const int tid = threadIdx.x;

    #pragma unroll
    for (int rep = 0; rep < 8; ++rep) {
        int idx = tid + 1024 * rep;            // 0..8191
        int arr = idx >> 11;                   // 0:Pm 1:Qm(+bm) 2:Pv 3:Qv(+bv)
        int node = (idx >> 5) & 63, t = idx & 31;
        int cb = (arr == 0) ? 0 : (arr == 1) ? 128 : (arr == 2) ? 256 : 384;
        float v = S[(size_t)(b * 64 + node) * SCOLS + cb + toff + t];
        if (arr == 1) v += bm[toff + t];
        if (arr == 3) v += bv[toff + t];
        L[arr * 64 * TS + node * TS + t] = v;
    }
    __syncthreads();

    const int tj = tid & 31, ti = tid >> 5;
    const int i0 = 2 * ti, j0 = 2 * tj;
    const float* Am  = L;
    const float* Bm2 = L + 64 * TS;
    const float* Av  = L + 2 * 64 * TS;
    const float* Bv2 = L + 3 * 64 * TS;
    float a00 = 0.f, a01 = 0.f, a10 = 0.f, a11 = 0.f;

    #pragma unroll
    for (int tc = 0; tc < 16; ++tc) {
        float2 amA = *(const float2*)&Am[i0 * TS + 2 * tc];
        float2 amB = *(const float2*)&Am[(i0 + 1) * TS + 2 * tc];
        float2 avA = *(const float2*)&Av[i0 * TS + 2 * tc];
        float2 avB = *(const float2*)&Av[(i0 + 1) * TS + 2 * tc];
        float2 bmA = *(const float2*)&Bm2[j0 * TS + 2 * tc];
        float2 bmB = *(const float2*)&Bm2[(j0 + 1) * TS + 2 * tc];
        float2 bvA = *(const float2*)&Bv2[j0 * TS + 2 * tc];
        float2 bvB = *(const float2*)&Bv2[(j0 + 1) * TS + 2 * tc];
        a00 += eterm(amA.x, bmA.x, avA.x, bvA.x) + eterm(amA.y, bmA.y, avA.y, bvA.y);
        a01 += eterm(amA.x, bmB.x, avA.x, bvB.x) + eterm(amA.y, bmB.y, avA.y, bvB.y);
        a10 += eterm(amB.x, bmA.x, avB.x, bvA.x) + eterm(amB.y, bmA.y, avB.y, bvA.y);
        a11 += eterm(amB.x, bmB.x, avB.x, bvB.x) + eterm(amB.y, bmB.y, avB.y, bvB.y);
    }

    float* p = partial + (size_t)tq * TOTE + (size_t)b * Ee;
    int i, j;
    i = i0;     j = j0;     if (i < j) p[(i * (127 - i)) / 2 + (j - i - 1)] = a00;
    i = i0;     j = j0 + 1; if (i < j) p[(i * (127 - i)) / 2 + (j - i - 1)] = a01;
    i = i0 + 1; j = j0;     if (i < j) p[(i * (127 - i)) / 2 + (j - i - 1)] = a10;
    i = i0 + 1; j = j0 + 1; if (i < j) p[(i * (127 - i)) / 2 + (j - i - 1)] = a11;
}

// ---------------- edge finalize: sim + logit ----------------
__global__ void k_fin(const float* __restrict__ partial, const float* __restrict__ S,
                      const int2* __restrict__ lut, const float* __restrict__ bw,
                      const float* __restrict__ gu, float* __restrict__ sim,
                      float* __restrict__ logit) {
    int e = blockIdx.x * 256 + threadIdx.x;
    if (e >= TOTE) return;
    int b = e / Ee, el = e - b * Ee;
    int2 rc = lut[el];
    float acc = partial[e] + partial[TOTE + e] + partial[2 * TOTE + e] + partial[3 * TOTE + e];
    float se = __expf(acc * (-0.5f / OUTD));
    float wr = S[(size_t)(b * 64 + rc.x) * SCOLS + 512]
             + S[(size_t)(b * 64 + rc.y) * SCOLS + 513] + bw[0];
    float w  = __builtin_amdgcn_rcpf(1.f + __expf(-wr));
    float g  = -__logf(-__logf(gu[e]));
    sim[e]   = se;
    logit[e] = (w + g) * 2.0f;   // / TEMPERATURE(=0.5)
}

// ---------------- global softmax reductions ----------------
__global__ void k_max(const float* __restrict__ logit, float* __restrict__ red) {
    __shared__ float sm[256];
    float m = -INFINITY;
    for (int i = blockIdx.x * 256 + threadIdx.x; i < TOTE; i += 256 * 256)
        m = fmaxf(m, logit[i]);
    sm[threadIdx.x] = m; __syncthreads();
    for (int s = 128; s; s >>= 1) {
        if (threadIdx.x < s) sm[threadIdx.x] = fmaxf(sm[threadIdx.x], sm[threadIdx.x + s]);
        __syncthreads();
    }
    if (!threadIdx.x) red[blockIdx.x] = sm[0];
}
__global__ void k_max2(float* __restrict__ red) {
    __shared__ float sm[256];
    sm[threadIdx.x] = red[threadIdx.x]; __syncthreads();
    for (int s = 128; s; s >>= 1) {
        if (threadIdx.x < s) sm[threadIdx.x] = fmaxf(sm[threadIdx.x], sm[threadIdx.x + s]);
        __syncthreads();
    }
    if (!threadIdx.x) red[256] = sm[0];
}
__global__ void k_sum(const float* __restrict__ logit, float* __restrict__ red) {
    __shared__ float sm[256];
    float M = red[256];
    float a = 0.f;
    for (int i = blockIdx.x * 256 + threadIdx.x; i < TOTE; i += 256 * 256)
        a += __expf(logit[i] - M);
    sm[threadIdx.x] = a; __syncthreads();
    for (int s = 128; s; s >>= 1) {
        if (threadIdx.x < s) sm[threadIdx.x] += sm[threadIdx.x + s];
        __syncthreads();
    }
    if (!threadIdx.x) red[blockIdx.x] = sm[0];
}
__global__ void k_sum2(float* __restrict__ red) {
    __shared__ float sm[256];
    sm[threadIdx.x] = red[threadIdx.x]; __syncthreads();
    for (int s = 128; s; s >>= 1) {
        if (threadIdx.x < s) sm[threadIdx.x] += sm[threadIdx.x + s];
        __syncthreads();
    }
    if (!threadIdx.x) red[257] = sm[0];
}

// ---------------- final scatter (also zero-fills) ----------------
__global__ void k_out(const float* __restrict__ sim, const float* __restrict__ logit,
                      const float* __restrict__ red, float* __restrict__ out) {
    int idx = blockIdx.x * 256 + threadIdx.x;
    if (idx >= Bg * Nn * Nn) return;
    int b = idx >> 12;
    int rem = idx & 4095;
    int r = rem >> 6, c = rem & 63;
    float v = 0.f;
    if (c > r) {
        int e = b * Ee + (r * (127 - r)) / 2 + (c - r - 1);
        float M = red[256], Sinv = __builtin_amdgcn_rcpf(red[257]);
        v = sim[e] * __expf(logit[e] - M) * Sinv;
    }
    out[idx] = v;
}

extern "C" void kernel_launch(void* const* d_in, const int* in_sizes, int n_in,
                              void* d_out, int out_size, void* d_ws, size_t ws_size,
                              hipStream_t stream) {
    const float* topo = (const float*)d_in[0];
    const float* temp = (const float*)d_in[1];
    const float* gu   = (const float*)d_in[2];
    const float* Wg   = (const float*)d_in[3];
    const float* bg   = (const float*)d_in[4];
    const float* Wm   = (const float*)d_in[5];
    const float* bm   = (const float*)d_in[6];
    const float* Wv   = (const float*)d_in[7];
    const float* bv   = (const float*)d_in[8];
    const float* Ww   = (const float*)d_in[9];
    const float* bw   = (const float*)d_in[10];
    float* out = (float*)d_out;

    char* ws = (char*)d_ws;
    size_t off = 0;
    auto carve = [&](size_t bytes) { char* p = ws + off; off = (off + bytes + 255) & ~(size_t)255; return p; };

    // Sbuf region (17.04 MB) also hosts aggb at its start (aggb dead before GEMM2 writes Sbuf).
    char*   r1    = carve((size_t)Bg * Nn * SCOLS * 4);
    float*  Sbuf  = (float*)r1;
    ushort* aggb  = (ushort*)r1;
    ushort* hb    = (ushort*)carve((size_t)Bg * Nn * Hd * 2);    // 4.19 MB
    ushort* Wgb   = (ushort*)carve((size_t)INF * Hd * 2);        // 0.16 MB
    ushort* Wcatb = (ushort*)carve((size_t)Hd * SCOLS * 2);      // 0.27 MB
    float*  part  = (float*)carve((size_t)4 * TOTE * 4);         // 4.13 MB
    float*  sim   = (float*)carve((size_t)TOTE * 4);             // 1.03 MB
    float*  lgt   = (float*)carve((size_t)TOTE * 4);             // 1.03 MB
    int2*   lut   = (int2*)carve((size_t)Ee * 8);
    float*  red   = (float*)carve(258 * 4);

    k_lut<<<(Ee + 255) / 256, 256, 0, stream>>>(lut);
    k_cvt<<<(INF * Hd + 255) / 256, 256, 0, stream>>>(Wg, Wgb, INF * Hd);
    k_pack<<<(Hd * SCOLS + 255) / 256, 256, 0, stream>>>(Wm, Wv, Ww, Wcatb);
    k_agg<<<Bg, INF, 0, stream>>>(topo, temp, aggb);
    // GEMM1: hb[8192,256] = relu(aggb[8192,320] @ Wgb[320,256] + bg)
    k_gemm_mfma<<<dim3(Hd / 64, (Bg * Nn) / 64), 256, 0, stream>>>(
        aggb, Wgb, bg, hb, nullptr, Hd, INF, 1);
    // GEMM2: Sbuf[8192,520] = hb[8192,256] @ Wcatb[256,520]
    k_gemm_mfma<<<dim3((SCOLS + 63) / 64, (Bg * Nn) / 64), 256, 0, stream>>>(
        hb, Wcatb, nullptr, nullptr, Sbuf, SCOLS, Hd, 0);
    k_edge2<<<Bg * 4, 1024, 0, stream>>>(Sbuf, bm, bv, part);
    k_fin<<<(TOTE + 255) / 256, 256, 0, stream>>>(part, Sbuf, lut, bw, gu, sim, lgt);
    k_max<<<256, 256, 0, stream>>>(lgt, red);
    k_max2<<<1, 256, 0, stream>>>(red);
    k_sum<<<256, 256, 0, stream>>>(lgt, red);
    k_sum2<<<1, 256, 0, stream>>>(red);
    k_out<<<(Bg * Nn * Nn + 255) / 256, 256, 0, stream>>>(sim, lgt, red, out);
}

// Round 4
// 204.914 us; speedup vs baseline: 1.4111x; 1.4111x over previous
//
#include <hip/hip_runtime.h>
#include <hip/hip_bf16.h>
#include <math.h>

#define Bg   128
#define Nn   64
#define Tt   256
#define INF  320      // Nn + Tt
#define Hd   256
#define OUTD 128
#define Ee   2016     // Nn*(Nn-1)/2
#define TOTE (Bg*Ee)  // 258048
#define SCOLS 576     // padded 514 -> 9*64 so GEMM2 tiles exactly
#define MROWS 8192    // Bg*Nn

typedef __attribute__((ext_vector_type(8))) short bf16x8;
typedef __attribute__((ext_vector_type(4))) float f32x4;

static __device__ __forceinline__ ushort f2bf(float v) {
    __hip_bfloat16 h = __float2bfloat16(v);
    return *(ushort*)&h;
}
static __device__ __forceinline__ unsigned fkey(float x) {
    unsigned b = __float_as_uint(x);
    return (b & 0x80000000u) ? ~b : (b | 0x80000000u);
}
static __device__ __forceinline__ float fkeyinv(unsigned k) {
    unsigned b = (k & 0x80000000u) ? (k ^ 0x80000000u) : ~k;
    return __uint_as_float(b);
}

// ---------------- fp32 -> bf16 convert ----------------
__global__ void k_cvt(const float* __restrict__ src, ushort* __restrict__ dst, int n) {
    int i = blockIdx.x * 256 + threadIdx.x;
    if (i < n) dst[i] = f2bf(src[i]);
}

// ---------------- pack head weights (bf16): Wcat[K=256][SCOLS] ----------------
__global__ void k_pack(const float* __restrict__ Wm, const float* __restrict__ Wv,
                       const float* __restrict__ Ww, ushort* __restrict__ Wcat) {
    int idx = blockIdx.x * 256 + threadIdx.x;
    if (idx >= Hd * SCOLS) return;
    int k = idx / SCOLS, col = idx - k * SCOLS;
    float v = 0.f;
    if (col < 128)       v = Wm[k * 128 + col];
    else if (col < 256)  v = Wm[(256 + k) * 128 + (col - 128)];
    else if (col < 384)  v = Wv[k * 128 + (col - 256)];
    else if (col < 512)  v = Wv[(256 + k) * 128 + (col - 384)];
    else if (col == 512) v = Ww[k];
    else if (col == 513) v = Ww[256 + k];
    Wcat[idx] = f2bf(v);
}

// ---------------- prefix-mean aggregation -> bf16 ----------------
__global__ void k_agg(const float* __restrict__ topo, const float* __restrict__ temp,
                      ushort* __restrict__ agg) {
    int b = blockIdx.x;
    int f = threadIdx.x;        // 320 threads
    float run = 0.f;
    for (int j = 0; j < Nn; ++j) {
        float v = (j == 0) ? 0.f : run / (float)j;
        agg[(size_t)(b * Nn + j) * INF + f] = f2bf(v);
        float x = (f < Nn) ? topo[(size_t)(b * Nn + j) * Nn + f]
                           : temp[(size_t)(b * Nn + j) * Tt + (f - Nn)];
        run += x;
    }
}

// ---------------- bf16 MFMA GEMM ----------------
// A: MxK bf16 row-major, B: KxN bf16 row-major. Tile 64x64, BK=32, 256 thr.
// transC=0: C row-major (Cb bf16 if non-null, else Cf fp32).
// transC=1: Cf fp32 transposed, leading dim MROWS (Cf[col][row]).
__global__ __launch_bounds__(256) void k_gemm_mfma(const ushort* __restrict__ A,
                                                   const ushort* __restrict__ B,
                                                   const float* __restrict__ bias,
                                                   ushort* __restrict__ Cb,
                                                   float* __restrict__ Cf,
                                                   int N, int K, int relu, int transC) {
    __shared__ ushort Asl[64 * 32];
    __shared__ ushort Bsl[64 * 32];   // transposed: Bsl[n][k]
    const int tid = threadIdx.x;
    const int w = tid >> 6, lane = tid & 63;
    const int quad = lane >> 4, r16 = lane & 15;
    const int m0 = blockIdx.y * 64, n0 = blockIdx.x * 64;
    const int arow = tid >> 2, aseg = tid & 3;
    const int bk = tid >> 3, bseg = tid & 7;
    f32x4 acc0 = {0,0,0,0}, acc1 = {0,0,0,0}, acc2 = {0,0,0,0}, acc3 = {0,0,0,0};

    for (int k0 = 0; k0 < K; k0 += 32) {
        uint4 av = *(const uint4*)(A + (size_t)(m0 + arow) * K + k0 + aseg * 8);
        *(uint4*)(Asl + arow * 32 + aseg * 8) = av;
        int bcol = n0 + bseg * 8;
        uint4 bvv = *(const uint4*)(B + (size_t)(k0 + bk) * N + bcol);
        ushort tmp[8];
        *(uint4*)tmp = bvv;
        #pragma unroll
        for (int t = 0; t < 8; ++t) Bsl[(bseg * 8 + t) * 32 + bk] = tmp[t];
        __syncthreads();

        bf16x8 af = *(const bf16x8*)(Asl + (w * 16 + r16) * 32 + quad * 8);
        bf16x8 bf0 = *(const bf16x8*)(Bsl + (0 * 16 + r16) * 32 + quad * 8);
        bf16x8 bf1 = *(const bf16x8*)(Bsl + (1 * 16 + r16) * 32 + quad * 8);
        bf16x8 bf2 = *(const bf16x8*)(Bsl + (2 * 16 + r16) * 32 + quad * 8);
        bf16x8 bf3 = *(const bf16x8*)(Bsl + (3 * 16 + r16) * 32 + quad * 8);
        acc0 = __builtin_amdgcn_mfma_f32_16x16x32_bf16(af, bf0, acc0, 0, 0, 0);
        acc1 = __builtin_amdgcn_mfma_f32_16x16x32_bf16(af, bf1, acc1, 0, 0, 0);
        acc2 = __builtin_amdgcn_mfma_f32_16x16x32_bf16(af, bf2, acc2, 0, 0, 0);
        acc3 = __builtin_amdgcn_mfma_f32_16x16x32_bf16(af, bf3, acc3, 0, 0, 0);
        __syncthreads();
    }

    const int row0 = m0 + w * 16 + quad * 4;
    #pragma unroll
    for (int ns = 0; ns < 4; ++ns) {
        f32x4 a = (ns == 0) ? acc0 : (ns == 1) ? acc1 : (ns == 2) ? acc2 : acc3;
        int col = n0 + ns * 16 + r16;
        float vv[4];
        #pragma unroll
        for (int i = 0; i < 4; ++i) {
            float v = a[i] + (bias ? bias[col] : 0.f);
            if (relu) v = fmaxf(v, 0.f);
            vv[i] = v;
        }
        if (transC) {
            *(float4*)(Cf + (size_t)col * MROWS + row0) = make_float4(vv[0], vv[1], vv[2], vv[3]);
        } else {
            #pragma unroll
            for (int i = 0; i < 4; ++i) {
                int row = row0 + i;
                if (Cb) Cb[(size_t)row * N + col] = f2bf(vv[i]);
                else    Cf[(size_t)row * N + col] = vv[i];
            }
        }
    }
}

// ---------------- quadrant-tiled edge kernel ----------------
// 384 blocks = 128 graphs x 3 quadrants {(lo,lo),(lo,hi),(hi,hi)}.
// LDS [4][128t][32n] = 64 KB, conflict-free ds_read_b64 compute.
// Full 128-t reduction in registers; writes final sim+logit.
static __device__ __forceinline__ float eterm(float pm, float qm, float pv, float qv) {
    float m = pm + qm;
    float x = pv + qv;
    float sp = fmaxf(x, 0.f) + __logf(1.f + __expf(-fabsf(x)));
    return m * m * __builtin_amdgcn_rcpf(sp + 1.01e-6f);
}

__global__ __launch_bounds__(256) void k_edge2(const float* __restrict__ ST,
                                               const float* __restrict__ bm,
                                               const float* __restrict__ bv,
                                               const float* __restrict__ bw,
                                               const float* __restrict__ gu,
                                               float* __restrict__ sim,
                                               float* __restrict__ lgt) {
    __shared__ float L[4][128][32];
    const int q = blockIdx.x % 3, b = blockIdx.x / 3;
    const int ih = (q == 2) ? 1 : 0, jh = (q == 0) ? 0 : 1;
    const int tid = threadIdx.x;

    for (int rep = 0; rep < 64; ++rep) {
        int idx = tid + 256 * rep;             // 0..16383
        int arr = idx >> 12;                   // 0:Pm(i) 1:Qm(j)+bm 2:Pv(i) 3:Qv(j)+bv
        int t = (idx >> 5) & 127, n = idx & 31;
        int side = (arr & 1) ? jh : ih;
        float v = ST[(size_t)(arr * 128 + t) * MROWS + b * 64 + side * 32 + n];
        if (arr == 1) v += bm[t];
        if (arr == 3) v += bv[t];
        L[arr][t][n] = v;
    }
    __syncthreads();

    const int ti = tid >> 4, tj = tid & 15;
    const int i0 = 2 * ti, j0 = 2 * tj;
    float a00 = 0.f, a01 = 0.f, a10 = 0.f, a11 = 0.f;

    #pragma unroll 4
    for (int t = 0; t < 128; ++t) {
        float2 mi = *(const float2*)&L[0][t][i0];
        float2 mj = *(const float2*)&L[1][t][j0];
        float2 vi = *(const float2*)&L[2][t][i0];
        float2 vj = *(const float2*)&L[3][t][j0];
        a00 += eterm(mi.x, mj.x, vi.x, vj.x);
        a01 += eterm(mi.x, mj.y, vi.x, vj.y);
        a10 += eterm(mi.y, mj.x, vi.y, vj.x);
        a11 += eterm(mi.y, mj.y, vi.y, vj.y);
    }

    float accs[2][2] = {{a00, a01}, {a10, a11}};
    #pragma unroll
    for (int di = 0; di < 2; ++di) {
        #pragma unroll
        for (int dj = 0; dj < 2; ++dj) {
            int gi = ih * 32 + i0 + di, gj = jh * 32 + j0 + dj;
            if (gi >= gj) continue;
            int e = b * Ee + (gi * (127 - gi)) / 2 + (gj - gi - 1);
            float se = __expf(accs[di][dj] * (-1.f / 256.f));   // exp(-0.5*acc/128)
            float wr = ST[(size_t)512 * MROWS + b * 64 + gi]
                     + ST[(size_t)513 * MROWS + b * 64 + gj] + bw[0];
            float w = __builtin_amdgcn_rcpf(1.f + __expf(-wr));
            float g = -__logf(-__logf(gu[e]));
            sim[e] = se;
            lgt[e] = (w + g) * 2.0f;   // / TEMPERATURE(=0.5)
        }
    }
}

// ---------------- softmax reductions (2 kernels, atomic) ----------------
__global__ void k_red1(const float* __restrict__ lgt, unsigned* __restrict__ red) {
    __shared__ float sm[256];
    float m = -INFINITY;
    for (int i = blockIdx.x * 256 + threadIdx.x; i < TOTE; i += 256 * 256)
        m = fmaxf(m, lgt[i]);
    sm[threadIdx.x] = m; __syncthreads();
    for (int s = 128; s; s >>= 1) {
        if (threadIdx.x < s) sm[threadIdx.x] = fmaxf(sm[threadIdx.x], sm[threadIdx.x + s]);
        __syncthreads();
    }
    if (!threadIdx.x) atomicMax(&red[0], fkey(sm[0]));
}
__global__ void k_red2(const float* __restrict__ lgt, unsigned* __restrict__ red) {
    __shared__ float sm[256];
    float M = fkeyinv(red[0]);
    float a = 0.f;
    for (int i = blockIdx.x * 256 + threadIdx.x; i < TOTE; i += 256 * 256)
        a += __expf(lgt[i] - M);
    sm[threadIdx.x] = a; __syncthreads();
    for (int s = 128; s; s >>= 1) {
        if (threadIdx.x < s) sm[threadIdx.x] += sm[threadIdx.x + s];
        __syncthreads();
    }
    if (!threadIdx.x) atomicAdd((float*)&red[1], sm[0]);
}

// ---------------- final scatter (also zero-fills) ----------------
__global__ void k_out(const float* __restrict__ sim, const float* __restrict__ lgt,
                      const unsigned* __restrict__ red, float* __restrict__ out) {
    int idx = blockIdx.x * 256 + threadIdx.x;
    if (idx >= Bg * Nn * Nn) return;
    int b = idx >> 12;
    int rem = idx & 4095;
    int r = rem >> 6, c = rem & 63;
    float v = 0.f;
    if (c > r) {
        int e = b * Ee + (r * (127 - r)) / 2 + (c - r - 1);
        float M = fkeyinv(red[0]);
        float Sinv = __builtin_amdgcn_rcpf(__uint_as_float(red[1]));
        v = sim[e] * __expf(lgt[e] - M) * Sinv;
    }
    out[idx] = v;
}

extern "C" void kernel_launch(void* const* d_in, const int* in_sizes, int n_in,
                              void* d_out, int out_size, void* d_ws, size_t ws_size,
                              hipStream_t stream) {
    const float* topo = (const float*)d_in[0];
    const float* temp = (const float*)d_in[1];
    const float* gu   = (const float*)d_in[2];
    const float* Wg   = (const float*)d_in[3];
    const float* bg   = (const float*)d_in[4];
    const float* Wm   = (const float*)d_in[5];
    const float* bm   = (const float*)d_in[6];
    const float* Wv   = (const float*)d_in[7];
    const float* bv   = (const float*)d_in[8];
    const float* Ww   = (const float*)d_in[9];
    const float* bw   = (const float*)d_in[10];
    float* out = (float*)d_out;

    char* ws = (char*)d_ws;
    size_t off = 0;
    auto carve = [&](size_t bytes) { char* p = ws + off; off = (off + bytes + 255) & ~(size_t)255; return p; };

    // r1 hosts aggb (bf16, 5.2 MB) pre-GEMM1, then S_T[576][8192] f32 (18.9 MB).
    char*   r1    = carve((size_t)SCOLS * MROWS * 4);
    float*  ST    = (float*)r1;
    ushort* aggb  = (ushort*)r1;
    ushort* hb    = (ushort*)carve((size_t)MROWS * Hd * 2);      // 4.19 MB
    ushort* Wgb   = (ushort*)carve((size_t)INF * Hd * 2);        // 0.16 MB
    ushort* Wcatb = (ushort*)carve((size_t)Hd * SCOLS * 2);      // 0.29 MB
    float*  sim   = (float*)carve((size_t)TOTE * 4);             // 1.03 MB
    float*  lgt   = (float*)carve((size_t)TOTE * 4);             // 1.03 MB
    unsigned* red = (unsigned*)carve(256);

    hipMemsetAsync(red, 0, 8, stream);
    k_cvt<<<(INF * Hd + 255) / 256, 256, 0, stream>>>(Wg, Wgb, INF * Hd);
    k_pack<<<(Hd * SCOLS + 255) / 256, 256, 0, stream>>>(Wm, Wv, Ww, Wcatb);
    k_agg<<<Bg, INF, 0, stream>>>(topo, temp, aggb);
    // GEMM1: hb[8192,256] = relu(aggb[8192,320] @ Wgb[320,256] + bg)
    k_gemm_mfma<<<dim3(Hd / 64, MROWS / 64), 256, 0, stream>>>(
        aggb, Wgb, bg, hb, nullptr, Hd, INF, 1, 0);
    // GEMM2: ST[576][8192] = (hb[8192,256] @ Wcatb[256,576])^T
    k_gemm_mfma<<<dim3(SCOLS / 64, MROWS / 64), 256, 0, stream>>>(
        hb, Wcatb, nullptr, nullptr, ST, SCOLS, Hd, 0, 1);
    k_edge2<<<Bg * 3, 256, 0, stream>>>(ST, bm, bv, bw, gu, sim, lgt);
    k_red1<<<256, 256, 0, stream>>>(lgt, red);
    k_red2<<<256, 256, 0, stream>>>(lgt, red);
    k_out<<<(Bg * Nn * Nn + 255) / 256, 256, 0, stream>>>(sim, lgt, red, out);
}

// Round 5
// 180.011 us; speedup vs baseline: 1.6063x; 1.1383x over previous
//
#include <hip/hip_runtime.h>
#include <hip/hip_bf16.h>
#include <math.h>

#define Bg   128
#define Nn   64
#define Tt   256
#define INF  320      // Nn + Tt
#define Hd   256
#define OUTD 128
#define Ee   2016     // Nn*(Nn-1)/2
#define TOTE (Bg*Ee)  // 258048
#define SCOLS 576     // padded 514 -> 9*64 so GEMM2 tiles exactly
#define MROWS 8192    // Bg*Nn

typedef __attribute__((ext_vector_type(8))) short bf16x8;
typedef __attribute__((ext_vector_type(4))) float f32x4;

static __device__ __forceinline__ ushort f2bf(float v) {
    __hip_bfloat16 h = __float2bfloat16(v);
    return *(ushort*)&h;
}
static __device__ __forceinline__ unsigned fkey(float x) {
    unsigned b = __float_as_uint(x);
    return (b & 0x80000000u) ? ~b : (b | 0x80000000u);
}
static __device__ __forceinline__ float fkeyinv(unsigned k) {
    unsigned b = (k & 0x80000000u) ? (k ^ 0x80000000u) : ~k;
    return __uint_as_float(b);
}

// ---------------- edge LUT: e -> (row, col) ----------------
__global__ void k_lut(int2* __restrict__ lut) {
    int e = blockIdx.x * 256 + threadIdx.x;
    if (e >= Ee) return;
    int r = 0;
    while ((r + 1) * (127 - (r + 1)) / 2 <= e) ++r;
    int c = r + 1 + (e - r * (127 - r) / 2);
    lut[e] = make_int2(r, c);
}

// ---------------- weight prep: Wg->bf16 and packed Wcat->bf16 ----------------
#define CVT_N (INF * Hd)                  // 81920
#define PACK_N (Hd * SCOLS)               // 147456
__global__ void k_prep(const float* __restrict__ Wg, const float* __restrict__ Wm,
                       const float* __restrict__ Wv, const float* __restrict__ Ww,
                       ushort* __restrict__ Wgb, ushort* __restrict__ Wcat) {
    int idx = blockIdx.x * 256 + threadIdx.x;
    if (idx < CVT_N) {
        Wgb[idx] = f2bf(Wg[idx]);
        return;
    }
    idx -= CVT_N;
    if (idx >= PACK_N) return;
    int k = idx / SCOLS, col = idx - k * SCOLS;
    float v = 0.f;
    if (col < 128)       v = Wm[k * 128 + col];
    else if (col < 256)  v = Wm[(256 + k) * 128 + (col - 128)];
    else if (col < 384)  v = Wv[k * 128 + (col - 256)];
    else if (col < 512)  v = Wv[(256 + k) * 128 + (col - 384)];
    else if (col == 512) v = Ww[k];
    else if (col == 513) v = Ww[256 + k];
    Wcat[idx] = f2bf(v);
}

// ---------------- prefix-mean aggregation -> bf16 ----------------
__global__ void k_agg(const float* __restrict__ topo, const float* __restrict__ temp,
                      ushort* __restrict__ agg) {
    int b = blockIdx.x;
    int f = threadIdx.x;        // 320 threads
    float run = 0.f;
    for (int j = 0; j < Nn; ++j) {
        float v = (j == 0) ? 0.f : run / (float)j;
        agg[(size_t)(b * Nn + j) * INF + f] = f2bf(v);
        float x = (f < Nn) ? topo[(size_t)(b * Nn + j) * Nn + f]
                           : temp[(size_t)(b * Nn + j) * Tt + (f - Nn)];
        run += x;
    }
}

// ---------------- bf16 MFMA GEMM ----------------
// A: MxK bf16 row-major, B: KxN bf16 row-major. Tile 64x64, BK=32, 256 thr.
// transC=0: C row-major (Cb bf16 if non-null, else Cf fp32).
// transC=1: Cf fp32 transposed, leading dim MROWS (Cf[col][row]).
__global__ __launch_bounds__(256) void k_gemm_mfma(const ushort* __restrict__ A,
                                                   const ushort* __restrict__ B,
                                                   const float* __restrict__ bias,
                                                   ushort* __restrict__ Cb,
                                                   float* __restrict__ Cf,
                                                   int N, int K, int relu, int transC) {
    __shared__ ushort Asl[64 * 32];
    __shared__ ushort Bsl[64 * 32];   // transposed: Bsl[n][k]
    const int tid = threadIdx.x;
    const int w = tid >> 6, lane = tid & 63;
    const int quad = lane >> 4, r16 = lane & 15;
    const int m0 = blockIdx.y * 64, n0 = blockIdx.x * 64;
    const int arow = tid >> 2, aseg = tid & 3;
    const int bk = tid >> 3, bseg = tid & 7;
    f32x4 acc0 = {0,0,0,0}, acc1 = {0,0,0,0}, acc2 = {0,0,0,0}, acc3 = {0,0,0,0};

    for (int k0 = 0; k0 < K; k0 += 32) {
        uint4 av = *(const uint4*)(A + (size_t)(m0 + arow) * K + k0 + aseg * 8);
        *(uint4*)(Asl + arow * 32 + aseg * 8) = av;
        int bcol = n0 + bseg * 8;
        uint4 bvv = *(const uint4*)(B + (size_t)(k0 + bk) * N + bcol);
        ushort tmp[8];
        *(uint4*)tmp = bvv;
        #pragma unroll
        for (int t = 0; t < 8; ++t) Bsl[(bseg * 8 + t) * 32 + bk] = tmp[t];
        __syncthreads();

        bf16x8 af = *(const bf16x8*)(Asl + (w * 16 + r16) * 32 + quad * 8);
        bf16x8 bf0 = *(const bf16x8*)(Bsl + (0 * 16 + r16) * 32 + quad * 8);
        bf16x8 bf1 = *(const bf16x8*)(Bsl + (1 * 16 + r16) * 32 + quad * 8);
        bf16x8 bf2 = *(const bf16x8*)(Bsl + (2 * 16 + r16) * 32 + quad * 8);
        bf16x8 bf3 = *(const bf16x8*)(Bsl + (3 * 16 + r16) * 32 + quad * 8);
        acc0 = __builtin_amdgcn_mfma_f32_16x16x32_bf16(af, bf0, acc0, 0, 0, 0);
        acc1 = __builtin_amdgcn_mfma_f32_16x16x32_bf16(af, bf1, acc1, 0, 0, 0);
        acc2 = __builtin_amdgcn_mfma_f32_16x16x32_bf16(af, bf2, acc2, 0, 0, 0);
        acc3 = __builtin_amdgcn_mfma_f32_16x16x32_bf16(af, bf3, acc3, 0, 0, 0);
        __syncthreads();
    }

    const int row0 = m0 + w * 16 + quad * 4;
    #pragma unroll
    for (int ns = 0; ns < 4; ++ns) {
        f32x4 a = (ns == 0) ? acc0 : (ns == 1) ? acc1 : (ns == 2) ? acc2 : acc3;
        int col = n0 + ns * 16 + r16;
        float vv[4];
        #pragma unroll
        for (int i = 0; i < 4; ++i) {
            float v = a[i] + (bias ? bias[col] : 0.f);
            if (relu) v = fmaxf(v, 0.f);
            vv[i] = v;
        }
        if (transC) {
            *(float4*)(Cf + (size_t)col * MROWS + row0) = make_float4(vv[0], vv[1], vv[2], vv[3]);
        } else {
            #pragma unroll
            for (int i = 0; i < 4; ++i) {
                int row = row0 + i;
                if (Cb) Cb[(size_t)row * N + col] = f2bf(vv[i]);
                else    Cf[(size_t)row * N + col] = vv[i];
            }
        }
    }
}

// ---------------- quadrant x t-slice edge partial kernel ----------------
// 1536 blocks = 128 graphs x 3 quadrants x 4 t-slices. LDS 16 KB.
// Each thread: 2x2 node pairs over 32 t. Writes partial[tq][edge].
static __device__ __forceinline__ float eterm(float pm, float qm, float pv, float qv) {
    float m = pm + qm;
    float x = pv + qv;
    float sp = fmaxf(x, 0.f) + __logf(1.f + __expf(-fabsf(x)));
    return m * m * __builtin_amdgcn_rcpf(sp + 1.01e-6f);
}

__global__ __launch_bounds__(256) void k_edge3(const float* __restrict__ ST,
                                               const float* __restrict__ bm,
                                               const float* __restrict__ bv,
                                               float* __restrict__ partial) {
    __shared__ float L[4][32][32];
    const int blk = blockIdx.x;
    const int tq = blk & 3;
    const int q  = (blk >> 2) % 3;
    const int b  = blk / 12;
    const int ih = (q == 2) ? 1 : 0, jh = (q == 0) ? 0 : 1;
    const int toff = tq * 32;
    const int tid = threadIdx.x;

    #pragma unroll
    for (int rep = 0; rep < 16; ++rep) {
        int idx = tid + 256 * rep;             // 0..4095
        int arr = idx >> 10;                   // 0:Pm(i) 1:Qm(j)+bm 2:Pv(i) 3:Qv(j)+bv
        int t = (idx >> 5) & 31, n = idx & 31;
        int side = (arr & 1) ? jh : ih;
        float v = ST[(size_t)(arr * 128 + toff + t) * MROWS + b * 64 + side * 32 + n];
        if (arr == 1) v += bm[toff + t];
        if (arr == 3) v += bv[toff + t];
        L[arr][t][n] = v;
    }
    __syncthreads();

    const int ti = tid >> 4, tj = tid & 15;
    const int i0 = 2 * ti, j0 = 2 * tj;
    float a00 = 0.f, a01 = 0.f, a10 = 0.f, a11 = 0.f;

    #pragma unroll 8
    for (int t = 0; t < 32; ++t) {
        float2 mi = *(const float2*)&L[0][t][i0];
        float2 mj = *(const float2*)&L[1][t][j0];
        float2 vi = *(const float2*)&L[2][t][i0];
        float2 vj = *(const float2*)&L[3][t][j0];
        a00 += eterm(mi.x, mj.x, vi.x, vj.x);
        a01 += eterm(mi.x, mj.y, vi.x, vj.y);
        a10 += eterm(mi.y, mj.x, vi.y, vj.x);
        a11 += eterm(mi.y, mj.y, vi.y, vj.y);
    }

    float accs[2][2] = {{a00, a01}, {a10, a11}};
    float* p = partial + (size_t)tq * TOTE + (size_t)b * Ee;
    #pragma unroll
    for (int di = 0; di < 2; ++di) {
        #pragma unroll
        for (int dj = 0; dj < 2; ++dj) {
            int gi = ih * 32 + i0 + di, gj = jh * 32 + j0 + dj;
            if (gi >= gj) continue;
            p[(gi * (127 - gi)) / 2 + (gj - gi - 1)] = accs[di][dj];
        }
    }
}

// ---------------- edge finalize: sim + logit ----------------
__global__ void k_fin(const float* __restrict__ partial, const float* __restrict__ ST,
                      const int2* __restrict__ lut, const float* __restrict__ bw,
                      const float* __restrict__ gu, float* __restrict__ sim,
                      float* __restrict__ lgt) {
    int e = blockIdx.x * 256 + threadIdx.x;
    if (e >= TOTE) return;
    int b = e / Ee, el = e - b * Ee;
    int2 rc = lut[el];
    float acc = partial[e] + partial[TOTE + e] + partial[2 * TOTE + e] + partial[3 * TOTE + e];
    float se = __expf(acc * (-1.f / 256.f));   // exp(-0.5*acc/128)
    float wr = ST[(size_t)512 * MROWS + b * 64 + rc.x]
             + ST[(size_t)513 * MROWS + b * 64 + rc.y] + bw[0];
    float w  = __builtin_amdgcn_rcpf(1.f + __expf(-wr));
    float g  = -__logf(-__logf(gu[e]));
    sim[e] = se;
    lgt[e] = (w + g) * 2.0f;   // / TEMPERATURE(=0.5)
}

// ---------------- softmax reductions (2 kernels, atomic) ----------------
__global__ void k_red1(const float* __restrict__ lgt, unsigned* __restrict__ red) {
    __shared__ float sm[256];
    float m = -INFINITY;
    for (int i = blockIdx.x * 256 + threadIdx.x; i < TOTE; i += 256 * 256)
        m = fmaxf(m, lgt[i]);
    sm[threadIdx.x] = m; __syncthreads();
    for (int s = 128; s; s >>= 1) {
        if (threadIdx.x < s) sm[threadIdx.x] = fmaxf(sm[threadIdx.x], sm[threadIdx.x + s]);
        __syncthreads();
    }
    if (!threadIdx.x) atomicMax(&red[0], fkey(sm[0]));
}
__global__ void k_red2(const float* __restrict__ lgt, unsigned* __restrict__ red) {
    __shared__ float sm[256];
    float M = fkeyinv(red[0]);
    float a = 0.f;
    for (int i = blockIdx.x * 256 + threadIdx.x; i < TOTE; i += 256 * 256)
        a += __expf(lgt[i] - M);
    sm[threadIdx.x] = a; __syncthreads();
    for (int s = 128; s; s >>= 1) {
        if (threadIdx.x < s) sm[threadIdx.x] += sm[threadIdx.x + s];
        __syncthreads();
    }
    if (!threadIdx.x) atomicAdd((float*)&red[1], sm[0]);
}

// ---------------- final scatter (also zero-fills) ----------------
__global__ void k_out(const float* __restrict__ sim, const float* __restrict__ lgt,
                      const unsigned* __restrict__ red, float* __restrict__ out) {
    int idx = blockIdx.x * 256 + threadIdx.x;
    if (idx >= Bg * Nn * Nn) return;
    int b = idx >> 12;
    int rem = idx & 4095;
    int r = rem >> 6, c = rem & 63;
    float v = 0.f;
    if (c > r) {
        int e = b * Ee + (r * (127 - r)) / 2 + (c - r - 1);
        float M = fkeyinv(red[0]);
        float Sinv = __builtin_amdgcn_rcpf(__uint_as_float(red[1]));
        v = sim[e] * __expf(lgt[e] - M) * Sinv;
    }
    out[idx] = v;
}

extern "C" void kernel_launch(void* const* d_in, const int* in_sizes, int n_in,
                              void* d_out, int out_size, void* d_ws, size_t ws_size,
                              hipStream_t stream) {
    const float* topo = (const float*)d_in[0];
    const float* temp = (const float*)d_in[1];
    const float* gu   = (const float*)d_in[2];
    const float* Wg   = (const float*)d_in[3];
    const float* bg   = (const float*)d_in[4];
    const float* Wm   = (const float*)d_in[5];
    const float* bm   = (const float*)d_in[6];
    const float* Wv   = (const float*)d_in[7];
    const float* bv   = (const float*)d_in[8];
    const float* Ww   = (const float*)d_in[9];
    const float* bw   = (const float*)d_in[10];
    float* out = (float*)d_out;

    char* ws = (char*)d_ws;
    size_t off = 0;
    auto carve = [&](size_t bytes) { char* p = ws + off; off = (off + bytes + 255) & ~(size_t)255; return p; };

    // r1 hosts aggb (bf16, 5.2 MB) pre-GEMM1, then S_T[576][8192] f32 (18.9 MB).
    char*   r1    = carve((size_t)SCOLS * MROWS * 4);
    float*  ST    = (float*)r1;
    ushort* aggb  = (ushort*)r1;
    ushort* hb    = (ushort*)carve((size_t)MROWS * Hd * 2);      // 4.19 MB
    ushort* Wgb   = (ushort*)carve((size_t)INF * Hd * 2);        // 0.16 MB
    ushort* Wcatb = (ushort*)carve((size_t)Hd * SCOLS * 2);      // 0.29 MB
    float*  part  = (float*)carve((size_t)4 * TOTE * 4);         // 4.13 MB
    float*  sim   = (float*)carve((size_t)TOTE * 4);             // 1.03 MB
    float*  lgt   = (float*)carve((size_t)TOTE * 4);             // 1.03 MB
    int2*   lut   = (int2*)carve((size_t)Ee * 8);
    unsigned* red = (unsigned*)carve(256);

    hipMemsetAsync(red, 0, 8, stream);
    k_lut<<<(Ee + 255) / 256, 256, 0, stream>>>(lut);
    k_prep<<<(CVT_N + PACK_N + 255) / 256, 256, 0, stream>>>(Wg, Wm, Wv, Ww, Wgb, Wcatb);
    k_agg<<<Bg, INF, 0, stream>>>(topo, temp, aggb);
    // GEMM1: hb[8192,256] = relu(aggb[8192,320] @ Wgb[320,256] + bg)
    k_gemm_mfma<<<dim3(Hd / 64, MROWS / 64), 256, 0, stream>>>(
        aggb, Wgb, bg, hb, nullptr, Hd, INF, 1, 0);
    // GEMM2: ST[576][8192] = (hb[8192,256] @ Wcatb[256,576])^T
    k_gemm_mfma<<<dim3(SCOLS / 64, MROWS / 64), 256, 0, stream>>>(
        hb, Wcatb, nullptr, nullptr, ST, SCOLS, Hd, 0, 1);
    k_edge3<<<Bg * 12, 256, 0, stream>>>(ST, bm, bv, part);
    k_fin<<<(TOTE + 255) / 256, 256, 0, stream>>>(part, ST, lut, bw, gu, sim, lgt);
    k_red1<<<256, 256, 0, stream>>>(lgt, red);
    k_red2<<<256, 256, 0, stream>>>(lgt, red);
    k_out<<<(Bg * Nn * Nn + 255) / 256, 256, 0, stream>>>(sim, lgt, red, out);
}